// Round 2
// baseline (698.583 us; speedup 1.0000x reference)
//
#include <hip/hip_runtime.h>

// MultiHeadAttention: B=4, S=2048, D=1024, H=16, DK=64
// cvt x->bf16; transpose weights->bf16 [N][K]; QKV GEMM (MFMA bf16, V written
// transposed [B,H,DK,S]); register-resident flash attention (S^T/O^T operand
// swap, P-only LDS round trip); output GEMM -> fp32.

typedef __attribute__((ext_vector_type(8))) short short8;
typedef __attribute__((ext_vector_type(4))) float floatx4;
typedef __attribute__((ext_vector_type(4))) unsigned short ushort4v;

__device__ __forceinline__ unsigned short f2bf(float f) {
    unsigned int u = __float_as_uint(f);
    unsigned int r = (u + 0x7fffu + ((u >> 16) & 1u)) >> 16;
    return (unsigned short)r;
}

__device__ __forceinline__ void gll16(const unsigned short* g, unsigned short* l) {
    __builtin_amdgcn_global_load_lds(
        (const __attribute__((address_space(1))) unsigned int*)g,
        (__attribute__((address_space(3))) unsigned int*)l, 16, 0, 0);
}

// ---------------- convert x (fp32 -> bf16) ----------------
__global__ void cvtx_kernel(const float* __restrict__ x, unsigned short* __restrict__ xb) {
    int i = (blockIdx.x * 256 + threadIdx.x) * 4;
    float4 v = *(const float4*)&x[i];
    ushort4v o;
    o.x = f2bf(v.x); o.y = f2bf(v.y); o.z = f2bf(v.z); o.w = f2bf(v.w);
    *(ushort4v*)&xb[i] = o;
}

// ---------------- transpose + convert weight: w[K][N] fp32 -> wt[N][K] bf16 ----------------
__global__ void wtrans_kernel(const float* __restrict__ w, unsigned short* __restrict__ wt) {
    __shared__ float t[32][33];
    int kb = blockIdx.y * 32, nb = blockIdx.x * 32;
    int col = threadIdx.x & 31, rw = threadIdx.x >> 5;
#pragma unroll
    for (int i = 0; i < 4; i++) {
        int row = rw + i * 8;
        t[row][col] = w[(kb + row) * 1024 + nb + col];
    }
    __syncthreads();
#pragma unroll
    for (int i = 0; i < 4; i++) {
        int row = rw + i * 8;
        wt[(nb + row) * 1024 + kb + col] = f2bf(t[col][row]);
    }
}

// ---------------- shared GEMM mainloop: C[128x128] = A[M][K] * Bt[N][K]^T ----------------
// Unpadded LDS (row stride 32 elems) so global_load_lds lane-contiguous dest works.
__device__ __forceinline__ void gemm_core(const unsigned short* __restrict__ A,
                                          const unsigned short* __restrict__ Bt,
                                          unsigned short* As, unsigned short* Bs,
                                          int m0, int n0, int K, floatx4 (&acc)[4][4]) {
    int tid = threadIdx.x;
    int lane = tid & 63, wave = tid >> 6;
    int wr = wave >> 1, wc = wave & 1;
    int quad = lane >> 4, l15 = lane & 15;
    floatx4 zero4 = {0.f, 0.f, 0.f, 0.f};
#pragma unroll
    for (int i = 0; i < 4; i++)
#pragma unroll
        for (int j = 0; j < 4; j++) acc[i][j] = zero4;

    for (int k0 = 0; k0 < K; k0 += 32) {
#pragma unroll
        for (int p = 0; p < 2; p++) {
            int c = p * 256 + tid;       // 0..511
            int row = c >> 2;            // 0..127
            int col8 = (c & 3) * 8;      // 0,8,16,24
            gll16(&A[(m0 + row) * K + k0 + col8], &As[c * 8]);
            gll16(&Bt[(n0 + row) * K + k0 + col8], &Bs[c * 8]);
        }
        __syncthreads();
        short8 af[4], bf[4];
#pragma unroll
        for (int mt = 0; mt < 4; mt++)
            af[mt] = *(short8*)&As[(wr * 64 + mt * 16 + l15) * 32 + quad * 8];
#pragma unroll
        for (int nt = 0; nt < 4; nt++)
            bf[nt] = *(short8*)&Bs[(wc * 64 + nt * 16 + l15) * 32 + quad * 8];
#pragma unroll
        for (int mt = 0; mt < 4; mt++)
#pragma unroll
            for (int nt = 0; nt < 4; nt++)
                acc[mt][nt] = __builtin_amdgcn_mfma_f32_16x16x32_bf16(af[mt], bf[nt], acc[mt][nt], 0, 0, 0);
        __syncthreads();
    }
}

// ---------------- QKV GEMM: Q,K -> [B,H,S,DK]; V -> [B,H,DK,S] (transposed) ----------------
__global__ __launch_bounds__(256) void gemm_qkv_kernel(
    const unsigned short* __restrict__ xb,
    const unsigned short* __restrict__ wtq, const unsigned short* __restrict__ wtk,
    const unsigned short* __restrict__ wtv,
    const float* __restrict__ bq, const float* __restrict__ bk, const float* __restrict__ bv,
    unsigned short* __restrict__ qo, unsigned short* __restrict__ ko, unsigned short* __restrict__ vo) {
    __shared__ __align__(16) unsigned short As[128 * 32];
    __shared__ __align__(16) unsigned short Bs[128 * 32];
    int m0 = blockIdx.y * 128, n0 = blockIdx.x * 128;
    const unsigned short* Bt;
    const float* bias;
    unsigned short* dst;
    int vmode = (blockIdx.z == 2);
    if (blockIdx.z == 0) { Bt = wtq; bias = bq; dst = qo; }
    else if (blockIdx.z == 1) { Bt = wtk; bias = bk; dst = ko; }
    else { Bt = wtv; bias = bv; dst = vo; }

    floatx4 acc[4][4];
    gemm_core(xb, Bt, As, Bs, m0, n0, 1024, acc);

    int tid = threadIdx.x, lane = tid & 63, wave = tid >> 6;
    int wr = wave >> 1, wc = wave & 1, quad = lane >> 4, l15 = lane & 15;
#pragma unroll
    for (int mt = 0; mt < 4; mt++)
#pragma unroll
        for (int nt = 0; nt < 4; nt++)
#pragma unroll
            for (int r = 0; r < 4; r++) {
                int rg = m0 + wr * 64 + mt * 16 + quad * 4 + r;   // token index b*S+s
                int cg = n0 + wc * 64 + nt * 16 + l15;            // feature index
                float v = acc[mt][nt][r] + bias[cg];
                int b = rg >> 11, s = rg & 2047;
                int h = cg >> 6, dk = cg & 63;
                long idx = vmode ? ((long)((b * 16 + h) * 64 + dk) * 2048 + s)
                                 : ((long)((b * 16 + h) * 2048 + s) * 64 + dk);
                dst[idx] = f2bf(v);
            }
}

// ---------------- output GEMM: fp32 out + bias ----------------
__global__ __launch_bounds__(256) void gemm_out_kernel(
    const unsigned short* __restrict__ ob, const unsigned short* __restrict__ wto,
    const float* __restrict__ bo, float* __restrict__ out) {
    __shared__ __align__(16) unsigned short As[128 * 32];
    __shared__ __align__(16) unsigned short Bs[128 * 32];
    int m0 = blockIdx.y * 128, n0 = blockIdx.x * 128;
    floatx4 acc[4][4];
    gemm_core(ob, wto, As, Bs, m0, n0, 1024, acc);

    int tid = threadIdx.x, lane = tid & 63, wave = tid >> 6;
    int wr = wave >> 1, wc = wave & 1, quad = lane >> 4, l15 = lane & 15;
#pragma unroll
    for (int mt = 0; mt < 4; mt++)
#pragma unroll
        for (int nt = 0; nt < 4; nt++)
#pragma unroll
            for (int r = 0; r < 4; r++) {
                int rg = m0 + wr * 64 + mt * 16 + quad * 4 + r;
                int cg = n0 + wc * 64 + nt * 16 + l15;
                out[rg * 1024 + cg] = acc[mt][nt][r] + bo[cg];
            }
}

// ---------------- flash attention (causal), register-resident, operand-swapped ----------------
// S^T = K Q^T (C-layout: row=key, col=q=l15) -> per-lane softmax (2 shfls) ->
// P via tiny per-wave LDS round trip -> O^T = V^T P^T. No __syncthreads.
#define PLS 72  // P row stride elems; 144B rows -> 16B aligned

__global__ __launch_bounds__(256) void attn_kernel(
    const unsigned short* __restrict__ Q, const unsigned short* __restrict__ Kk,
    const unsigned short* __restrict__ Vt, unsigned short* __restrict__ O) {
    __shared__ __align__(16) unsigned short Ps[4 * 16 * PLS];

    int q0 = blockIdx.x * 64;
    int bh = blockIdx.y;
    long base = (long)bh * 2048 * 64;   // Q, K: [bh][s][dk]
    long vbase = (long)bh * 64 * 2048;  // Vt:   [bh][dk][s]
    int tid = threadIdx.x, lane = tid & 63, wave = tid >> 6;
    int quad = lane >> 4, l15 = lane & 15;
    const float SCL = 0.125f * 1.44269504f;  // 1/sqrt(64) * log2(e)

    // Q fragments (B-operand of K*Q^T): lane value = Q[q=l15][dk=quad*8+j]
    short8 qf[2];
    int qrow = q0 + wave * 16 + l15;
    qf[0] = *(const short8*)&Q[base + qrow * 64 + quad * 8];
    qf[1] = *(const short8*)&Q[base + qrow * 64 + 32 + quad * 8];
    int qg = qrow;

    float m_i = -1e30f, l_i = 0.f;
    floatx4 oacc[4];  // O^T: dk=st*16+quad*4+r, q=l15
    floatx4 zero4 = {0.f, 0.f, 0.f, 0.f};
#pragma unroll
    for (int st = 0; st < 4; st++) oacc[st] = zero4;

    unsigned short* myP = &Ps[(wave * 16) * PLS];

    int ktmax = q0 >> 6;
    for (int kt = 0; kt <= ktmax; kt++) {
        long kb = base + (long)(kt * 64) * 64;
        // S^T = K Q^T
        floatx4 sa[4];
#pragma unroll
        for (int st = 0; st < 4; st++) {
            short8 kf0 = *(const short8*)&Kk[kb + (st * 16 + l15) * 64 + quad * 8];
            short8 kf1 = *(const short8*)&Kk[kb + (st * 16 + l15) * 64 + 32 + quad * 8];
            sa[st] = __builtin_amdgcn_mfma_f32_16x16x32_bf16(kf0, qf[0], zero4, 0, 0, 0);
            sa[st] = __builtin_amdgcn_mfma_f32_16x16x32_bf16(kf1, qf[1], sa[st], 0, 0, 0);
        }

        // scale into log2 domain + causal mask; per-lane row stats (q = l15)
        float t[4][4];
        float rm = -1e30f;
#pragma unroll
        for (int st = 0; st < 4; st++)
#pragma unroll
            for (int r = 0; r < 4; r++) {
                int kg = kt * 64 + st * 16 + quad * 4 + r;
                float v = (kg > qg) ? -1e30f : sa[st][r] * SCL;
                t[st][r] = v;
                rm = fmaxf(rm, v);
            }
        rm = fmaxf(rm, __shfl_xor(rm, 16, 64));
        rm = fmaxf(rm, __shfl_xor(rm, 32, 64));
        float mn = fmaxf(m_i, rm);
        float alpha = exp2f(m_i - mn);
        float rs = 0.f;
#pragma unroll
        for (int st = 0; st < 4; st++)
#pragma unroll
            for (int r = 0; r < 4; r++) {
                float p = exp2f(t[st][r] - mn);
                t[st][r] = p;
                rs += p;
            }
        rs += __shfl_xor(rs, 16, 64);
        rs += __shfl_xor(rs, 32, 64);
        l_i = l_i * alpha + rs;
        m_i = mn;
#pragma unroll
        for (int st = 0; st < 4; st++)
#pragma unroll
            for (int r = 0; r < 4; r++) oacc[st][r] *= alpha;

        // P -> LDS: row q=l15, cols key=st*16+quad*4+{0..3} (4x b64 writes)
#pragma unroll
        for (int st = 0; st < 4; st++) {
            ushort4v pk;
            pk.x = f2bf(t[st][0]); pk.y = f2bf(t[st][1]);
            pk.z = f2bf(t[st][2]); pk.w = f2bf(t[st][3]);
            *(ushort4v*)&myP[l15 * PLS + st * 16 + quad * 4] = pk;
        }
        // P^T B-frags: lane value = P[q=l15][key=kk*32+quad*8+j]
        short8 pf0 = *(short8*)&myP[l15 * PLS + quad * 8];
        short8 pf1 = *(short8*)&myP[l15 * PLS + 32 + quad * 8];

        // O^T += V^T P^T (A = V^T from Vt[dk][s] rows, contiguous)
#pragma unroll
        for (int st = 0; st < 4; st++) {
            short8 vf0 = *(const short8*)&Vt[vbase + (st * 16 + l15) * 2048 + kt * 64 + quad * 8];
            short8 vf1 = *(const short8*)&Vt[vbase + (st * 16 + l15) * 2048 + kt * 64 + 32 + quad * 8];
            oacc[st] = __builtin_amdgcn_mfma_f32_16x16x32_bf16(vf0, pf0, oacc[st], 0, 0, 0);
            oacc[st] = __builtin_amdgcn_mfma_f32_16x16x32_bf16(vf1, pf1, oacc[st], 0, 0, 0);
        }
    }

    // epilogue: O^T regs -> O[b,s,h*64+dk] bf16, 8B stores (4 contiguous dk)
    float inv = 1.f / l_i;
    int b = bh >> 4, h = bh & 15;
    int s = qg;
#pragma unroll
    for (int st = 0; st < 4; st++) {
        ushort4v ov;
        ov.x = f2bf(oacc[st][0] * inv); ov.y = f2bf(oacc[st][1] * inv);
        ov.z = f2bf(oacc[st][2] * inv); ov.w = f2bf(oacc[st][3] * inv);
        *(ushort4v*)&O[((long)(b * 2048 + s)) * 1024 + h * 64 + st * 16 + quad * 4] = ov;
    }
}

// ---------------- launch ----------------
extern "C" void kernel_launch(void* const* d_in, const int* in_sizes, int n_in,
                              void* d_out, int out_size, void* d_ws, size_t ws_size,
                              hipStream_t stream) {
    const float* x  = (const float*)d_in[0];
    const float* wq = (const float*)d_in[1];
    const float* bq = (const float*)d_in[2];
    const float* wk = (const float*)d_in[3];
    const float* bk = (const float*)d_in[4];
    const float* wv = (const float*)d_in[5];
    const float* bv = (const float*)d_in[6];
    const float* wo = (const float*)d_in[7];
    const float* bo = (const float*)d_in[8];

    char* w = (char*)d_ws;
    unsigned short* xb  = (unsigned short*)w;                    // 8M elems (16MB)
    unsigned short* wtq = (unsigned short*)(w + (16u << 20));    // 1M elems each
    unsigned short* wtk = wtq + (1u << 20);
    unsigned short* wtv = wtk + (1u << 20);
    unsigned short* wto = wtv + (1u << 20);
    unsigned short* qb  = wto + (1u << 20);                      // 8M elems each
    unsigned short* kb  = qb + (8u << 20);
    unsigned short* vb  = kb + (8u << 20);                       // V^T [B,H,DK,S]
    unsigned short* ob  = vb + (8u << 20);                       // ends at 88MB

    cvtx_kernel<<<8192, 256, 0, stream>>>(x, xb);
    dim3 tg(32, 32);
    wtrans_kernel<<<tg, 256, 0, stream>>>(wq, wtq);
    wtrans_kernel<<<tg, 256, 0, stream>>>(wk, wtk);
    wtrans_kernel<<<tg, 256, 0, stream>>>(wv, wtv);
    wtrans_kernel<<<tg, 256, 0, stream>>>(wo, wto);
    gemm_qkv_kernel<<<dim3(8, 64, 3), 256, 0, stream>>>(xb, wtq, wtk, wtv, bq, bk, bv, qb, kb, vb);
    attn_kernel<<<dim3(32, 64), 256, 0, stream>>>(qb, kb, vb, ob);
    gemm_out_kernel<<<dim3(8, 64), 256, 0, stream>>>(ob, wto, bo, (float*)d_out);
}

// Round 3
// 344.022 us; speedup vs baseline: 2.0306x; 2.0306x over previous
//
#include <hip/hip_runtime.h>

// MultiHeadAttention: B=4, S=2048, D=1024, H=16, DK=64
// cvt x->bf16; transpose weights->bf16 [N][K]; QKV GEMM (MFMA bf16, V written
// transposed [B,H,DK,S]); flash attention with operand-swapped softmax,
// double-buffered XOR-swizzled LDS K/V staging; output GEMM -> fp32.

typedef __attribute__((ext_vector_type(8))) short short8;
typedef __attribute__((ext_vector_type(4))) float floatx4;
typedef __attribute__((ext_vector_type(4))) unsigned short ushort4v;

__device__ __forceinline__ unsigned short f2bf(float f) {
    unsigned int u = __float_as_uint(f);
    unsigned int r = (u + 0x7fffu + ((u >> 16) & 1u)) >> 16;
    return (unsigned short)r;
}

__device__ __forceinline__ void gll16(const unsigned short* g, unsigned short* l) {
    __builtin_amdgcn_global_load_lds(
        (const __attribute__((address_space(1))) unsigned int*)g,
        (__attribute__((address_space(3))) unsigned int*)l, 16, 0, 0);
}

// ---------------- convert x (fp32 -> bf16) ----------------
__global__ void cvtx_kernel(const float* __restrict__ x, unsigned short* __restrict__ xb) {
    int i = (blockIdx.x * 256 + threadIdx.x) * 4;
    float4 v = *(const float4*)&x[i];
    ushort4v o;
    o.x = f2bf(v.x); o.y = f2bf(v.y); o.z = f2bf(v.z); o.w = f2bf(v.w);
    *(ushort4v*)&xb[i] = o;
}

// ---------------- transpose + convert weight: w[K][N] fp32 -> wt[N][K] bf16 ----------------
__global__ void wtrans_kernel(const float* __restrict__ w, unsigned short* __restrict__ wt) {
    __shared__ float t[32][33];
    int kb = blockIdx.y * 32, nb = blockIdx.x * 32;
    int col = threadIdx.x & 31, rw = threadIdx.x >> 5;
#pragma unroll
    for (int i = 0; i < 4; i++) {
        int row = rw + i * 8;
        t[row][col] = w[(kb + row) * 1024 + nb + col];
    }
    __syncthreads();
#pragma unroll
    for (int i = 0; i < 4; i++) {
        int row = rw + i * 8;
        wt[(nb + row) * 1024 + kb + col] = f2bf(t[col][row]);
    }
}

// ---------------- shared GEMM mainloop: C[128x128] = A[M][K] * Bt[N][K]^T ----------------
__device__ __forceinline__ void gemm_core(const unsigned short* __restrict__ A,
                                          const unsigned short* __restrict__ Bt,
                                          unsigned short* As, unsigned short* Bs,
                                          int m0, int n0, int K, floatx4 (&acc)[4][4]) {
    int tid = threadIdx.x;
    int lane = tid & 63, wave = tid >> 6;
    int wr = wave >> 1, wc = wave & 1;
    int quad = lane >> 4, l15 = lane & 15;
    floatx4 zero4 = {0.f, 0.f, 0.f, 0.f};
#pragma unroll
    for (int i = 0; i < 4; i++)
#pragma unroll
        for (int j = 0; j < 4; j++) acc[i][j] = zero4;

    for (int k0 = 0; k0 < K; k0 += 32) {
#pragma unroll
        for (int p = 0; p < 2; p++) {
            int c = p * 256 + tid;       // 0..511
            int row = c >> 2;            // 0..127
            int col8 = (c & 3) * 8;      // 0,8,16,24
            gll16(&A[(m0 + row) * K + k0 + col8], &As[c * 8]);
            gll16(&Bt[(n0 + row) * K + k0 + col8], &Bs[c * 8]);
        }
        __syncthreads();
        short8 af[4], bf[4];
#pragma unroll
        for (int mt = 0; mt < 4; mt++)
            af[mt] = *(short8*)&As[(wr * 64 + mt * 16 + l15) * 32 + quad * 8];
#pragma unroll
        for (int nt = 0; nt < 4; nt++)
            bf[nt] = *(short8*)&Bs[(wc * 64 + nt * 16 + l15) * 32 + quad * 8];
#pragma unroll
        for (int mt = 0; mt < 4; mt++)
#pragma unroll
            for (int nt = 0; nt < 4; nt++)
                acc[mt][nt] = __builtin_amdgcn_mfma_f32_16x16x32_bf16(af[mt], bf[nt], acc[mt][nt], 0, 0, 0);
        __syncthreads();
    }
}

// ---------------- QKV GEMM: Q,K -> [B,H,S,DK]; V -> [B,H,DK,S] (transposed) ----------------
__global__ __launch_bounds__(256) void gemm_qkv_kernel(
    const unsigned short* __restrict__ xb,
    const unsigned short* __restrict__ wtq, const unsigned short* __restrict__ wtk,
    const unsigned short* __restrict__ wtv,
    const float* __restrict__ bq, const float* __restrict__ bk, const float* __restrict__ bv,
    unsigned short* __restrict__ qo, unsigned short* __restrict__ ko, unsigned short* __restrict__ vo) {
    __shared__ __align__(16) unsigned short As[128 * 32];
    __shared__ __align__(16) unsigned short Bs[128 * 32];
    int m0 = blockIdx.y * 128, n0 = blockIdx.x * 128;
    const unsigned short* Bt;
    const float* bias;
    unsigned short* dst;
    int vmode = (blockIdx.z == 2);
    if (blockIdx.z == 0) { Bt = wtq; bias = bq; dst = qo; }
    else if (blockIdx.z == 1) { Bt = wtk; bias = bk; dst = ko; }
    else { Bt = wtv; bias = bv; dst = vo; }

    floatx4 acc[4][4];
    gemm_core(xb, Bt, As, Bs, m0, n0, 1024, acc);

    int tid = threadIdx.x, lane = tid & 63, wave = tid >> 6;
    int wr = wave >> 1, wc = wave & 1, quad = lane >> 4, l15 = lane & 15;
#pragma unroll
    for (int mt = 0; mt < 4; mt++)
#pragma unroll
        for (int nt = 0; nt < 4; nt++)
#pragma unroll
            for (int r = 0; r < 4; r++) {
                int rg = m0 + wr * 64 + mt * 16 + quad * 4 + r;   // token index b*S+s
                int cg = n0 + wc * 64 + nt * 16 + l15;            // feature index
                float v = acc[mt][nt][r] + bias[cg];
                int b = rg >> 11, s = rg & 2047;
                int h = cg >> 6, dk = cg & 63;
                long idx = vmode ? ((long)((b * 16 + h) * 64 + dk) * 2048 + s)
                                 : ((long)((b * 16 + h) * 2048 + s) * 64 + dk);
                dst[idx] = f2bf(v);
            }
}

// ---------------- output GEMM: fp32 out + bias ----------------
__global__ __launch_bounds__(256) void gemm_out_kernel(
    const unsigned short* __restrict__ ob, const unsigned short* __restrict__ wto,
    const float* __restrict__ bo, float* __restrict__ out) {
    __shared__ __align__(16) unsigned short As[128 * 32];
    __shared__ __align__(16) unsigned short Bs[128 * 32];
    int m0 = blockIdx.y * 128, n0 = blockIdx.x * 128;
    floatx4 acc[4][4];
    gemm_core(ob, wto, As, Bs, m0, n0, 1024, acc);

    int tid = threadIdx.x, lane = tid & 63, wave = tid >> 6;
    int wr = wave >> 1, wc = wave & 1, quad = lane >> 4, l15 = lane & 15;
#pragma unroll
    for (int mt = 0; mt < 4; mt++)
#pragma unroll
        for (int nt = 0; nt < 4; nt++)
#pragma unroll
            for (int r = 0; r < 4; r++) {
                int rg = m0 + wr * 64 + mt * 16 + quad * 4 + r;
                int cg = n0 + wc * 64 + nt * 16 + l15;
                out[rg * 1024 + cg] = acc[mt][nt][r] + bo[cg];
            }
}

// ---------------- flash attention (causal) ----------------
// S^T = K Q^T -> per-lane softmax (2 shfls) -> P LDS round trip -> O^T = V^T P^T.
// K and V^T tiles staged to LDS via global_load_lds(16B) with XOR-swizzled
// granules (phys_g = logical_g ^ (row&7)) -> conflict-floor ds_read_b128.
// Double-buffered; heavy q-tiles dispatched first.
#define PLS 72

__device__ __forceinline__ void stage_kv(const unsigned short* __restrict__ Kg,
                                         const unsigned short* __restrict__ Vg,
                                         unsigned short* Ks, unsigned short* Vs,
                                         int lane, int wave) {
    int rsub = lane >> 3;            // 0..7
    int g = (lane & 7) ^ rsub;       // logical granule for this lane's phys slot
#pragma unroll
    for (int p = 0; p < 2; p++) {
        int chunk = wave * 2 + p;    // 0..7
        int r = chunk * 8 + rsub;    // row 0..63 (K: key, V^T: dk)
        gll16(&Kg[r * 64 + g * 8], &Ks[chunk * 512]);
        gll16(&Vg[r * 2048 + g * 8], &Vs[chunk * 512]);
    }
}

__global__ __launch_bounds__(256) void attn_kernel(
    const unsigned short* __restrict__ Q, const unsigned short* __restrict__ Kk,
    const unsigned short* __restrict__ Vt, unsigned short* __restrict__ O) {
    __shared__ __align__(16) unsigned short Ks[2][8 * 512];
    __shared__ __align__(16) unsigned short Vs[2][8 * 512];
    __shared__ __align__(16) unsigned short Ps[4 * 16 * PLS];

    int bid = blockIdx.x;
    int qt = 31 - (bid >> 6);        // heavy q-tiles first
    int bh = bid & 63;
    int q0 = qt * 64;
    long base = (long)bh * 2048 * 64;   // Q, K: [bh][s][dk]
    long vbase = (long)bh * 64 * 2048;  // Vt:   [bh][dk][s]
    int tid = threadIdx.x, lane = tid & 63, wave = tid >> 6;
    int quad = lane >> 4, l15 = lane & 15;
    const float SCL = 0.125f * 1.44269504f;  // 1/sqrt(64) * log2(e)

    // Q fragments (B-operand of K*Q^T): lane value = Q[q=l15][dk=quad*8+j]
    short8 qf[2];
    int qrow = q0 + wave * 16 + l15;
    qf[0] = *(const short8*)&Q[base + qrow * 64 + quad * 8];
    qf[1] = *(const short8*)&Q[base + qrow * 64 + 32 + quad * 8];
    int qg = qrow;

    float m_i = -1e30f, l_i = 0.f;
    floatx4 oacc[4];  // O^T: dk=st*16+quad*4+r, q=l15
    floatx4 zero4 = {0.f, 0.f, 0.f, 0.f};
#pragma unroll
    for (int st = 0; st < 4; st++) oacc[st] = zero4;

    unsigned short* myP = &Ps[(wave * 16) * PLS];
    int l7 = l15 & 7;

    int ktmax = qt;
    stage_kv(&Kk[base], &Vt[vbase], Ks[0], Vs[0], lane, wave);
    __syncthreads();

    for (int kt = 0; kt <= ktmax; kt++) {
        int cur = kt & 1;
        if (kt < ktmax)
            stage_kv(&Kk[base + (long)(kt + 1) * 64 * 64], &Vt[vbase + (kt + 1) * 64],
                     Ks[cur ^ 1], Vs[cur ^ 1], lane, wave);

        // S^T = K Q^T
        floatx4 sa[4];
#pragma unroll
        for (int st = 0; st < 4; st++) {
            int row = st * 16 + l15;
            short8 kf0 = *(short8*)&Ks[cur][row * 64 + ((quad ^ l7) * 8)];
            short8 kf1 = *(short8*)&Ks[cur][row * 64 + (((4 + quad) ^ l7) * 8)];
            sa[st] = __builtin_amdgcn_mfma_f32_16x16x32_bf16(kf0, qf[0], zero4, 0, 0, 0);
            sa[st] = __builtin_amdgcn_mfma_f32_16x16x32_bf16(kf1, qf[1], sa[st], 0, 0, 0);
        }

        // scale + causal mask; per-lane row stats (q = l15)
        float t[4][4];
        float rm = -1e30f;
#pragma unroll
        for (int st = 0; st < 4; st++)
#pragma unroll
            for (int r = 0; r < 4; r++) {
                int kg = kt * 64 + st * 16 + quad * 4 + r;
                float v = (kg > qg) ? -1e30f : sa[st][r] * SCL;
                t[st][r] = v;
                rm = fmaxf(rm, v);
            }
        rm = fmaxf(rm, __shfl_xor(rm, 16, 64));
        rm = fmaxf(rm, __shfl_xor(rm, 32, 64));
        float mn = fmaxf(m_i, rm);
        float alpha = exp2f(m_i - mn);
        float rs = 0.f;
#pragma unroll
        for (int st = 0; st < 4; st++)
#pragma unroll
            for (int r = 0; r < 4; r++) {
                float p = exp2f(t[st][r] - mn);
                t[st][r] = p;
                rs += p;
            }
        rs += __shfl_xor(rs, 16, 64);
        rs += __shfl_xor(rs, 32, 64);
        l_i = l_i * alpha + rs;
        m_i = mn;
#pragma unroll
        for (int st = 0; st < 4; st++)
#pragma unroll
            for (int r = 0; r < 4; r++) oacc[st][r] *= alpha;

        // P -> LDS (row q=l15, col key) -> P^T B-frags
#pragma unroll
        for (int st = 0; st < 4; st++) {
            ushort4v pk;
            pk.x = f2bf(t[st][0]); pk.y = f2bf(t[st][1]);
            pk.z = f2bf(t[st][2]); pk.w = f2bf(t[st][3]);
            *(ushort4v*)&myP[l15 * PLS + st * 16 + quad * 4] = pk;
        }
        short8 pf0 = *(short8*)&myP[l15 * PLS + quad * 8];
        short8 pf1 = *(short8*)&myP[l15 * PLS + 32 + quad * 8];

        // O^T += V^T P^T
#pragma unroll
        for (int st = 0; st < 4; st++) {
            int row = st * 16 + l15;
            short8 vf0 = *(short8*)&Vs[cur][row * 64 + ((quad ^ l7) * 8)];
            short8 vf1 = *(short8*)&Vs[cur][row * 64 + (((4 + quad) ^ l7) * 8)];
            oacc[st] = __builtin_amdgcn_mfma_f32_16x16x32_bf16(vf0, pf0, oacc[st], 0, 0, 0);
            oacc[st] = __builtin_amdgcn_mfma_f32_16x16x32_bf16(vf1, pf1, oacc[st], 0, 0, 0);
        }
        __syncthreads();
    }

    // epilogue: O^T regs -> O[b,s,h*64+dk] bf16, 8B stores
    float inv = 1.f / l_i;
    int b = bh >> 4, h = bh & 15;
    int s = qg;
#pragma unroll
    for (int st = 0; st < 4; st++) {
        ushort4v ov;
        ov.x = f2bf(oacc[st][0] * inv); ov.y = f2bf(oacc[st][1] * inv);
        ov.z = f2bf(oacc[st][2] * inv); ov.w = f2bf(oacc[st][3] * inv);
        *(ushort4v*)&O[((long)(b * 2048 + s)) * 1024 + h * 64 + st * 16 + quad * 4] = ov;
    }
}

// ---------------- launch ----------------
extern "C" void kernel_launch(void* const* d_in, const int* in_sizes, int n_in,
                              void* d_out, int out_size, void* d_ws, size_t ws_size,
                              hipStream_t stream) {
    const float* x  = (const float*)d_in[0];
    const float* wq = (const float*)d_in[1];
    const float* bq = (const float*)d_in[2];
    const float* wk = (const float*)d_in[3];
    const float* bk = (const float*)d_in[4];
    const float* wv = (const float*)d_in[5];
    const float* bv = (const float*)d_in[6];
    const float* wo = (const float*)d_in[7];
    const float* bo = (const float*)d_in[8];

    char* w = (char*)d_ws;
    unsigned short* xb  = (unsigned short*)w;                    // 16MB
    unsigned short* wtq = (unsigned short*)(w + (16u << 20));
    unsigned short* wtk = wtq + (1u << 20);
    unsigned short* wtv = wtk + (1u << 20);
    unsigned short* wto = wtv + (1u << 20);
    unsigned short* qb  = wto + (1u << 20);
    unsigned short* kb  = qb + (8u << 20);
    unsigned short* vb  = kb + (8u << 20);                       // V^T [B,H,DK,S]
    unsigned short* ob  = vb + (8u << 20);

    cvtx_kernel<<<8192, 256, 0, stream>>>(x, xb);
    dim3 tg(32, 32);
    wtrans_kernel<<<tg, 256, 0, stream>>>(wq, wtq);
    wtrans_kernel<<<tg, 256, 0, stream>>>(wk, wtk);
    wtrans_kernel<<<tg, 256, 0, stream>>>(wv, wtv);
    wtrans_kernel<<<tg, 256, 0, stream>>>(wo, wto);
    gemm_qkv_kernel<<<dim3(8, 64, 3), 256, 0, stream>>>(xb, wtq, wtk, wtv, bq, bk, bv, qb, kb, vb);
    attn_kernel<<<2048, 256, 0, stream>>>(qb, kb, vb, ob);
    gemm_out_kernel<<<dim3(8, 64), 256, 0, stream>>>(ob, wto, bo, (float*)d_out);
}